// Round 1
// baseline (710.284 us; speedup 1.0000x reference)
//
#include <hip/hip_runtime.h>
#include <hip/hip_bf16.h>

#define GCN_N 100000

// ---------------- CSR build ----------------

__global__ __launch_bounds__(256) void k_count(const int* __restrict__ dst,
                                               int* __restrict__ cnt, int E) {
    int i = blockIdx.x * 256 + threadIdx.x;
    if (i < E) atomicAdd(&cnt[dst[i]], 1);
}

// Exclusive scan of cnt[0..n) -> rowstart[0..n], single block of 1024.
__global__ __launch_bounds__(1024) void k_scan(const int* __restrict__ cnt,
                                               int* __restrict__ rowstart, int n) {
    __shared__ int wsum[16];
    __shared__ int sbase;
    const int lane = threadIdx.x & 63;
    const int wid  = threadIdx.x >> 6;
    if (threadIdx.x == 0) sbase = 0;
    __syncthreads();
    for (int start = 0; start < n; start += 1024) {
        int i = start + threadIdx.x;
        int v = (i < n) ? cnt[i] : 0;
        int s = v;
        #pragma unroll
        for (int off = 1; off < 64; off <<= 1) {
            int t = __shfl_up(s, off, 64);
            if (lane >= off) s += t;
        }
        if (lane == 63) wsum[wid] = s;   // inclusive wave totals
        __syncthreads();
        if (threadIdx.x == 0) {
            int run = sbase;
            #pragma unroll
            for (int w = 0; w < 16; ++w) { int t = wsum[w]; wsum[w] = run; run += t; }
            sbase = run;
        }
        __syncthreads();
        if (i < n) rowstart[i] = wsum[wid] + (s - v);   // global exclusive prefix
        __syncthreads();
    }
    if (threadIdx.x == 0) rowstart[n] = sbase;
}

__global__ __launch_bounds__(256) void k_dinv(const int* __restrict__ cnt,
                                              float* __restrict__ dinv, int n) {
    int i = blockIdx.x * 256 + threadIdx.x;
    if (i < n) dinv[i] = rsqrtf((float)(cnt[i] + 1));   // +1 self-loop; always > 0
}

__global__ __launch_bounds__(256) void k_fill(const int* __restrict__ src,
                                              const int* __restrict__ dst,
                                              const int* __restrict__ rowstart,
                                              int* __restrict__ cursor,
                                              int* __restrict__ csr_src, int E) {
    int i = blockIdx.x * 256 + threadIdx.x;
    if (i < E) {
        int d = dst[i];
        int p = atomicAdd(&cursor[d], 1);
        csr_src[rowstart[d] + p] = src[i];
    }
}

// ---------------- H[M x 128] = X[M x 128] @ W[128 x 128], f32 ----------------
// 32 rows/block, 256 threads, each thread a 4x4 register patch.
__global__ __launch_bounds__(256) void k_gemm(const float* __restrict__ X,
                                              const float* __restrict__ W,
                                              float* __restrict__ H) {
    __shared__ float Wl[64 * 128];   // [k_local][c]  32 KB
    __shared__ float Xt[64 * 32];    // [k_local][r]   8 KB
    const int t  = threadIdx.x;
    const int tc = t & 31;           // cols 4*tc .. 4*tc+3
    const int tr = t >> 5;           // rows 4*tr .. 4*tr+3
    const long long row0 = (long long)blockIdx.x * 32;
    float acc[4][4] = {};
    for (int kc = 0; kc < 128; kc += 64) {
        __syncthreads();
        {   // stage W[kc..kc+63][:]  (2048 float4)
            const float4* Wv = (const float4*)(W + kc * 128);
            float4* Wd = (float4*)Wl;
            for (int i = t; i < 2048; i += 256) Wd[i] = Wv[i];
        }
        {   // stage Xt[k][r] = X[row0+r][kc+k]  (512 float4 reads, transposed store)
            for (int idx = t; idx < 512; idx += 256) {
                int r  = idx >> 4;    // 0..31
                int kq = idx & 15;    // 0..15
                float4 v = *(const float4*)(X + (row0 + r) * 128 + kc + kq * 4);
                Xt[(kq * 4 + 0) * 32 + r] = v.x;
                Xt[(kq * 4 + 1) * 32 + r] = v.y;
                Xt[(kq * 4 + 2) * 32 + r] = v.z;
                Xt[(kq * 4 + 3) * 32 + r] = v.w;
            }
        }
        __syncthreads();
        #pragma unroll 8
        for (int k = 0; k < 64; ++k) {
            float4 w  = *(const float4*)(Wl + k * 128 + tc * 4);
            float4 xr = *(const float4*)(Xt + k * 32 + tr * 4);
            float xv[4] = {xr.x, xr.y, xr.z, xr.w};
            float wv[4] = {w.x, w.y, w.z, w.w};
            #pragma unroll
            for (int i = 0; i < 4; ++i)
                #pragma unroll
                for (int j = 0; j < 4; ++j)
                    acc[i][j] = fmaf(xv[i], wv[j], acc[i][j]);
        }
    }
    float* Hp = H + (row0 + tr * 4) * 128 + tc * 4;
    #pragma unroll
    for (int i = 0; i < 4; ++i) {
        float4 o = {acc[i][0], acc[i][1], acc[i][2], acc[i][3]};
        *(float4*)(Hp + i * 128) = o;
    }
}

// ---------------- aggregate: out[d] = relu(sum_{e:dst=d} h[s]*dinv[s]*dinv[d]
//                                           + h[d]*dinv[d]^2 + b) ----------------
// One wave per node; 64 lanes x float2 = 128 channels in registers.
__global__ __launch_bounds__(256) void k_agg(const float* __restrict__ h,
                                             const int* __restrict__ rowstart,
                                             const int* __restrict__ csr_src,
                                             const float* __restrict__ dinv,
                                             const float* __restrict__ bias,
                                             float* __restrict__ out, int n) {
    const int wid  = threadIdx.x >> 6;
    const int lane = threadIdx.x & 63;
    const int node = blockIdx.x * 4 + wid;
    if (node >= n) return;
    const float di = dinv[node];
    const int beg = rowstart[node], end = rowstart[node + 1];
    const float2* hv = (const float2*)h;
    float2 hself = hv[node * 64 + lane];
    float ax = hself.x * di * di;
    float ay = hself.y * di * di;
    for (int e = beg; e < end; ++e) {
        int s = csr_src[e];
        float w = dinv[s] * di;
        float2 hs = hv[s * 64 + lane];
        ax = fmaf(hs.x, w, ax);
        ay = fmaf(hs.y, w, ay);
    }
    float2 b = ((const float2*)bias)[lane];
    float2 o;
    o.x = fmaxf(ax + b.x, 0.0f);
    o.y = fmaxf(ay + b.y, 0.0f);
    ((float2*)out)[node * 64 + lane] = o;
}

// ---------------- launch ----------------

extern "C" void kernel_launch(void* const* d_in, const int* in_sizes, int n_in,
                              void* d_out, int out_size, void* d_ws, size_t ws_size,
                              hipStream_t stream) {
    const float* x   = (const float*)d_in[0];
    const int* edges = (const int*)d_in[1];
    const float* W1  = (const float*)d_in[2];
    const float* b1  = (const float*)d_in[3];
    const float* W2  = (const float*)d_in[4];
    const float* b2  = (const float*)d_in[5];
    const int E = in_sizes[1] / 2;
    const int N = GCN_N;
    const int* srcp = edges;
    const int* dstp = edges + E;

    char* ws = (char*)d_ws;
    int*   cnt      = (int*)(ws + 0);          // 400000 B
    int*   rowstart = (int*)(ws + 524288);     // 400004 B
    int*   cursor   = (int*)(ws + 1048576);    // 400000 B
    float* dinvp    = (float*)(ws + 1572864);  // 400000 B
    int*   csr      = (int*)(ws + 2097152);    // 6.4 MB
    float* h1       = (float*)(ws + 8912896);  // 51.2 MB
    float* h2       = (float*)(ws + 60112896); // 51.2 MB (end ~111.3 MB)

    hipMemsetAsync(cnt, 0, N * sizeof(int), stream);
    hipMemsetAsync(cursor, 0, N * sizeof(int), stream);

    const int eb = (E + 255) / 256;
    k_count<<<eb, 256, 0, stream>>>(dstp, cnt, E);
    k_scan<<<1, 1024, 0, stream>>>(cnt, rowstart, N);
    k_dinv<<<(N + 255) / 256, 256, 0, stream>>>(cnt, dinvp, N);
    k_fill<<<eb, 256, 0, stream>>>(srcp, dstp, rowstart, cursor, csr, E);

    // layer 1
    k_gemm<<<N / 32, 256, 0, stream>>>(x, W1, h1);
    k_agg<<<(N + 3) / 4, 256, 0, stream>>>(h1, rowstart, csr, dinvp, b1, h2, N);
    // layer 2 (h3 reuses h1)
    k_gemm<<<N / 32, 256, 0, stream>>>(h2, W2, h1);
    k_agg<<<(N + 3) / 4, 256, 0, stream>>>(h1, rowstart, csr, dinvp, b2, (float*)d_out, N);
}

// Round 2
// 524.607 us; speedup vs baseline: 1.3539x; 1.3539x over previous
//
#include <hip/hip_runtime.h>
#include <hip/hip_bf16.h>

#define GCN_N 100000

// ---------------- CSR build ----------------

__global__ __launch_bounds__(256) void k_count(const int* __restrict__ dst,
                                               int* __restrict__ cnt, int E) {
    int i = blockIdx.x * 256 + threadIdx.x;
    if (i < E) atomicAdd(&cnt[dst[i]], 1);
}

// Phase 1: per-block sums of cnt (256 elements per block)
__global__ __launch_bounds__(256) void k_bsum(const int* __restrict__ cnt,
                                              int* __restrict__ bsum, int n) {
    int i = blockIdx.x * 256 + threadIdx.x;
    int v = (i < n) ? cnt[i] : 0;
    #pragma unroll
    for (int off = 32; off > 0; off >>= 1) v += __shfl_down(v, off, 64);
    __shared__ int ws[4];
    const int lane = threadIdx.x & 63, wid = threadIdx.x >> 6;
    if (lane == 0) ws[wid] = v;
    __syncthreads();
    if (threadIdx.x == 0) bsum[blockIdx.x] = ws[0] + ws[1] + ws[2] + ws[3];
}

// Phase 2: exclusive scan of nb block sums (nb <= 512), one block.
__global__ __launch_bounds__(512) void k_bscan(const int* __restrict__ bsum,
                                               int* __restrict__ bbase,
                                               int* __restrict__ rowstart,
                                               int nb, int n) {
    __shared__ int wsum[8];
    __shared__ int woff[8];
    __shared__ int total;
    const int lane = threadIdx.x & 63, wid = threadIdx.x >> 6;
    int v = (threadIdx.x < nb) ? bsum[threadIdx.x] : 0;
    int s = v;
    #pragma unroll
    for (int off = 1; off < 64; off <<= 1) {
        int t = __shfl_up(s, off, 64);
        if (lane >= off) s += t;
    }
    if (lane == 63) wsum[wid] = s;
    __syncthreads();
    if (threadIdx.x == 0) {
        int run = 0;
        #pragma unroll
        for (int w = 0; w < 8; ++w) { int t = wsum[w]; woff[w] = run; run += t; }
        total = run;
    }
    __syncthreads();
    if (threadIdx.x < nb) bbase[threadIdx.x] = woff[wid] + (s - v);
    if (threadIdx.x == 0) rowstart[n] = total;
}

// Phase 3: per-block exclusive scan + bbase -> rowstart; also dinv & cursor=0.
__global__ __launch_bounds__(256) void k_rows(const int* __restrict__ cnt,
                                              const int* __restrict__ bbase,
                                              int* __restrict__ rowstart,
                                              float* __restrict__ dinv,
                                              int* __restrict__ cursor, int n) {
    __shared__ int wsum[4];
    __shared__ int woff[4];
    const int lane = threadIdx.x & 63, wid = threadIdx.x >> 6;
    int i = blockIdx.x * 256 + threadIdx.x;
    int v = (i < n) ? cnt[i] : 0;
    int s = v;
    #pragma unroll
    for (int off = 1; off < 64; off <<= 1) {
        int t = __shfl_up(s, off, 64);
        if (lane >= off) s += t;
    }
    if (lane == 63) wsum[wid] = s;
    __syncthreads();
    if (threadIdx.x == 0) {
        int run = bbase[blockIdx.x];
        #pragma unroll
        for (int w = 0; w < 4; ++w) { int t = wsum[w]; woff[w] = run; run += t; }
    }
    __syncthreads();
    if (i < n) {
        rowstart[i] = woff[wid] + (s - v);
        dinv[i] = rsqrtf((float)(v + 1));   // +1 self-loop
        cursor[i] = 0;
    }
}

__global__ __launch_bounds__(256) void k_fill(const int* __restrict__ src,
                                              const int* __restrict__ dst,
                                              const int* __restrict__ rowstart,
                                              int* __restrict__ cursor,
                                              int* __restrict__ csr_src, int E) {
    int i = blockIdx.x * 256 + threadIdx.x;
    if (i < E) {
        int d = dst[i];
        int p = atomicAdd(&cursor[d], 1);
        csr_src[rowstart[d] + p] = src[i];
    }
}

// ---------------- H[M x 128] = (X[M x 128] @ W[128 x 128]) * dinv[row], f32 ----
// 32 rows/block, 256 threads, each thread a 4x4 register patch.
__global__ __launch_bounds__(256) void k_gemm(const float* __restrict__ X,
                                              const float* __restrict__ W,
                                              const float* __restrict__ dinv,
                                              float* __restrict__ H) {
    __shared__ float Wl[64 * 128];   // [k_local][c]  32 KB
    __shared__ float Xt[64 * 32];    // [k_local][r]   8 KB
    const int t  = threadIdx.x;
    const int tc = t & 31;           // cols 4*tc .. 4*tc+3
    const int tr = t >> 5;           // rows 4*tr .. 4*tr+3
    const long long row0 = (long long)blockIdx.x * 32;
    float acc[4][4] = {};
    for (int kc = 0; kc < 128; kc += 64) {
        __syncthreads();
        {   // stage W[kc..kc+63][:]  (2048 float4)
            const float4* Wv = (const float4*)(W + kc * 128);
            float4* Wd = (float4*)Wl;
            for (int i = t; i < 2048; i += 256) Wd[i] = Wv[i];
        }
        {   // stage Xt[k][r] = X[row0+r][kc+k]
            for (int idx = t; idx < 512; idx += 256) {
                int r  = idx >> 4;    // 0..31
                int kq = idx & 15;    // 0..15
                float4 v = *(const float4*)(X + (row0 + r) * 128 + kc + kq * 4);
                Xt[(kq * 4 + 0) * 32 + r] = v.x;
                Xt[(kq * 4 + 1) * 32 + r] = v.y;
                Xt[(kq * 4 + 2) * 32 + r] = v.z;
                Xt[(kq * 4 + 3) * 32 + r] = v.w;
            }
        }
        __syncthreads();
        #pragma unroll 8
        for (int k = 0; k < 64; ++k) {
            float4 w  = *(const float4*)(Wl + k * 128 + tc * 4);
            float4 xr = *(const float4*)(Xt + k * 32 + tr * 4);
            float xv[4] = {xr.x, xr.y, xr.z, xr.w};
            float wv[4] = {w.x, w.y, w.z, w.w};
            #pragma unroll
            for (int i = 0; i < 4; ++i)
                #pragma unroll
                for (int j = 0; j < 4; ++j)
                    acc[i][j] = fmaf(xv[i], wv[j], acc[i][j]);
        }
    }
    // epilogue: scale row r by dinv[r] so aggregation needs no dinv gathers
    #pragma unroll
    for (int i = 0; i < 4; ++i) {
        float dv = dinv[row0 + tr * 4 + i];
        float* Hp = H + (row0 + tr * 4 + i) * 128 + tc * 4;
        float4 o = {acc[i][0] * dv, acc[i][1] * dv, acc[i][2] * dv, acc[i][3] * dv};
        *(float4*)Hp = o;
    }
}

// ---------------- aggregate ----------------
// h is pre-scaled by dinv[src]:  out[d] = relu((sum_s h[s] + h[d]) * dinv[d] + b)
// One wave per node; 64 lanes x float2 = 128 channels; 4 gathers in flight.
__global__ __launch_bounds__(256) void k_agg(const float* __restrict__ h,
                                             const int* __restrict__ rowstart,
                                             const int* __restrict__ csr_src,
                                             const float* __restrict__ dinv,
                                             const float* __restrict__ bias,
                                             float* __restrict__ out, int n) {
    const int wid  = threadIdx.x >> 6;
    const int lane = threadIdx.x & 63;
    const int node = blockIdx.x * 4 + wid;
    if (node >= n) return;
    const float di = dinv[node];
    int e = rowstart[node];
    const int end = rowstart[node + 1];
    const float2* __restrict__ hv = (const float2*)h;
    float2 hs = hv[(size_t)node * 64 + lane];
    float ax0 = hs.x, ay0 = hs.y;     // self term (already *dinv[node])
    float ax1 = 0.f, ay1 = 0.f;
    for (; e + 4 <= end; e += 4) {
        int s0 = csr_src[e + 0];
        int s1 = csr_src[e + 1];
        int s2 = csr_src[e + 2];
        int s3 = csr_src[e + 3];
        float2 a = hv[(size_t)s0 * 64 + lane];
        float2 b = hv[(size_t)s1 * 64 + lane];
        float2 c = hv[(size_t)s2 * 64 + lane];
        float2 d = hv[(size_t)s3 * 64 + lane];
        ax0 += a.x + b.x;  ay0 += a.y + b.y;
        ax1 += c.x + d.x;  ay1 += c.y + d.y;
    }
    for (; e < end; ++e) {
        int s = csr_src[e];
        float2 a = hv[(size_t)s * 64 + lane];
        ax0 += a.x;  ay0 += a.y;
    }
    float2 bv = ((const float2*)bias)[lane];
    float2 o;
    o.x = fmaxf(fmaf(ax0 + ax1, di, bv.x), 0.0f);
    o.y = fmaxf(fmaf(ay0 + ay1, di, bv.y), 0.0f);
    ((float2*)out)[(size_t)node * 64 + lane] = o;
}

// ---------------- launch ----------------

extern "C" void kernel_launch(void* const* d_in, const int* in_sizes, int n_in,
                              void* d_out, int out_size, void* d_ws, size_t ws_size,
                              hipStream_t stream) {
    const float* x   = (const float*)d_in[0];
    const int* edges = (const int*)d_in[1];
    const float* W1  = (const float*)d_in[2];
    const float* b1  = (const float*)d_in[3];
    const float* W2  = (const float*)d_in[4];
    const float* b2  = (const float*)d_in[5];
    const int E = in_sizes[1] / 2;
    const int N = GCN_N;
    const int* srcp = edges;
    const int* dstp = edges + E;
    const int NB = (N + 255) / 256;            // 391 scan blocks

    char* ws = (char*)d_ws;
    int*   cnt      = (int*)(ws + 0);          // 400000 B
    int*   rowstart = (int*)(ws + 524288);     // 400004 B
    int*   cursor   = (int*)(ws + 1048576);    // 400000 B
    float* dinvp    = (float*)(ws + 1572864);  // 400000 B
    int*   bsum     = (int*)(ws + 1998848);    // 1564 B
    int*   bbase    = (int*)(ws + 2031616);    // 1564 B
    int*   csr      = (int*)(ws + 2097152);    // 6.4 MB
    float* h1       = (float*)(ws + 8912896);  // 51.2 MB
    float* h2       = (float*)(ws + 60112896); // 51.2 MB (end ~111.3 MB)

    hipMemsetAsync(cnt, 0, N * sizeof(int), stream);

    const int eb = (E + 255) / 256;
    k_count<<<eb, 256, 0, stream>>>(dstp, cnt, E);
    k_bsum <<<NB, 256, 0, stream>>>(cnt, bsum, N);
    k_bscan<<<1, 512, 0, stream>>>(bsum, bbase, rowstart, NB, N);
    k_rows <<<NB, 256, 0, stream>>>(cnt, bbase, rowstart, dinvp, cursor, N);
    k_fill <<<eb, 256, 0, stream>>>(srcp, dstp, rowstart, cursor, csr, E);

    // layer 1
    k_gemm<<<N / 32, 256, 0, stream>>>(x, W1, dinvp, h1);
    k_agg<<<(N + 3) / 4, 256, 0, stream>>>(h1, rowstart, csr, dinvp, b1, h2, N);
    // layer 2
    k_gemm<<<N / 32, 256, 0, stream>>>(h2, W2, dinvp, h1);
    k_agg<<<(N + 3) / 4, 256, 0, stream>>>(h1, rowstart, csr, dinvp, b2, (float*)d_out, N);
}

// Round 3
// 437.792 us; speedup vs baseline: 1.6224x; 1.1983x over previous
//
#include <hip/hip_runtime.h>
#include <hip/hip_bf16.h>

#define GCN_N 100000
#define GEMM_BLOCKS (GCN_N / 32)   // 3125

// ---------------- CSR build ----------------

// Count degrees AND record each edge's rank within its dst row (atomic return).
__global__ __launch_bounds__(256) void k_rank(const int* __restrict__ dst,
                                              int* __restrict__ cnt,
                                              int* __restrict__ rank, int E) {
    int i = blockIdx.x * 256 + threadIdx.x;
    if (i < E) rank[i] = atomicAdd(&cnt[dst[i]], 1);
}

// Phase 1: per-block sums of cnt (256 elements per block)
__global__ __launch_bounds__(256) void k_bsum(const int* __restrict__ cnt,
                                              int* __restrict__ bsum, int n) {
    int i = blockIdx.x * 256 + threadIdx.x;
    int v = (i < n) ? cnt[i] : 0;
    #pragma unroll
    for (int off = 32; off > 0; off >>= 1) v += __shfl_down(v, off, 64);
    __shared__ int ws[4];
    const int lane = threadIdx.x & 63, wid = threadIdx.x >> 6;
    if (lane == 0) ws[wid] = v;
    __syncthreads();
    if (threadIdx.x == 0) bsum[blockIdx.x] = ws[0] + ws[1] + ws[2] + ws[3];
}

// Phase 2: exclusive scan of nb block sums (nb <= 512), one block.
__global__ __launch_bounds__(512) void k_bscan(const int* __restrict__ bsum,
                                               int* __restrict__ bbase,
                                               int* __restrict__ rowstart,
                                               int nb, int n) {
    __shared__ int wsum[8];
    __shared__ int woff[8];
    __shared__ int total;
    const int lane = threadIdx.x & 63, wid = threadIdx.x >> 6;
    int v = (threadIdx.x < nb) ? bsum[threadIdx.x] : 0;
    int s = v;
    #pragma unroll
    for (int off = 1; off < 64; off <<= 1) {
        int t = __shfl_up(s, off, 64);
        if (lane >= off) s += t;
    }
    if (lane == 63) wsum[wid] = s;
    __syncthreads();
    if (threadIdx.x == 0) {
        int run = 0;
        #pragma unroll
        for (int w = 0; w < 8; ++w) { int t = wsum[w]; woff[w] = run; run += t; }
        total = run;
    }
    __syncthreads();
    if (threadIdx.x < nb) bbase[threadIdx.x] = woff[wid] + (s - v);
    if (threadIdx.x == 0) rowstart[n] = total;
}

// Phase 3: per-block exclusive scan + bbase -> rowstart; also dinv.
__global__ __launch_bounds__(256) void k_rows(const int* __restrict__ cnt,
                                              const int* __restrict__ bbase,
                                              int* __restrict__ rowstart,
                                              float* __restrict__ dinv, int n) {
    __shared__ int wsum[4];
    __shared__ int woff[4];
    const int lane = threadIdx.x & 63, wid = threadIdx.x >> 6;
    int i = blockIdx.x * 256 + threadIdx.x;
    int v = (i < n) ? cnt[i] : 0;
    int s = v;
    #pragma unroll
    for (int off = 1; off < 64; off <<= 1) {
        int t = __shfl_up(s, off, 64);
        if (lane >= off) s += t;
    }
    if (lane == 63) wsum[wid] = s;
    __syncthreads();
    if (threadIdx.x == 0) {
        int run = bbase[blockIdx.x];
        #pragma unroll
        for (int w = 0; w < 4; ++w) { int t = wsum[w]; woff[w] = run; run += t; }
    }
    __syncthreads();
    if (i < n) {
        rowstart[i] = woff[wid] + (s - v);
        dinv[i] = rsqrtf((float)(v + 1));   // +1 self-loop
    }
}

// ---------------- fused: GEMM1 (x@W1 * dinv) + atomic-free CSR scatter -------
// Blocks [0, GEMM_BLOCKS): gemm 32 rows each. Blocks [GEMM_BLOCKS, +SB): scatter.
__global__ __launch_bounds__(256) void k_gemm1_scatter(
        const float* __restrict__ X, const float* __restrict__ W,
        const float* __restrict__ dinv, float* __restrict__ H,
        const int* __restrict__ src, const int* __restrict__ dst,
        const int* __restrict__ rank, const int* __restrict__ rowstart,
        int* __restrict__ csr_src, int E) {
    __shared__ float Wl[64 * 128];   // 32 KB
    __shared__ float Xt[64 * 32];    //  8 KB
    if (blockIdx.x >= GEMM_BLOCKS) {
        int i = (blockIdx.x - GEMM_BLOCKS) * 256 + threadIdx.x;
        if (i < E) {
            int d = dst[i];
            csr_src[rowstart[d] + rank[i]] = src[i];   // no atomic
        }
        return;
    }
    const int t  = threadIdx.x;
    const int tc = t & 31;
    const int tr = t >> 5;
    const long long row0 = (long long)blockIdx.x * 32;
    float acc[4][4] = {};
    for (int kc = 0; kc < 128; kc += 64) {
        __syncthreads();
        {
            const float4* Wv = (const float4*)(W + kc * 128);
            float4* Wd = (float4*)Wl;
            for (int i = t; i < 2048; i += 256) Wd[i] = Wv[i];
        }
        {
            for (int idx = t; idx < 512; idx += 256) {
                int r  = idx >> 4;
                int kq = idx & 15;
                float4 v = *(const float4*)(X + (row0 + r) * 128 + kc + kq * 4);
                Xt[(kq * 4 + 0) * 32 + r] = v.x;
                Xt[(kq * 4 + 1) * 32 + r] = v.y;
                Xt[(kq * 4 + 2) * 32 + r] = v.z;
                Xt[(kq * 4 + 3) * 32 + r] = v.w;
            }
        }
        __syncthreads();
        #pragma unroll 8
        for (int k = 0; k < 64; ++k) {
            float4 w  = *(const float4*)(Wl + k * 128 + tc * 4);
            float4 xr = *(const float4*)(Xt + k * 32 + tr * 4);
            float xv[4] = {xr.x, xr.y, xr.z, xr.w};
            float wv[4] = {w.x, w.y, w.z, w.w};
            #pragma unroll
            for (int i = 0; i < 4; ++i)
                #pragma unroll
                for (int j = 0; j < 4; ++j)
                    acc[i][j] = fmaf(xv[i], wv[j], acc[i][j]);
        }
    }
    #pragma unroll
    for (int i = 0; i < 4; ++i) {
        float dv = dinv[row0 + tr * 4 + i];
        float* Hp = H + (row0 + tr * 4 + i) * 128 + tc * 4;
        float4 o = {acc[i][0] * dv, acc[i][1] * dv, acc[i][2] * dv, acc[i][3] * dv};
        *(float4*)Hp = o;
    }
}

// ---------------- standalone GEMM (layer 2): H = (X@W) * dinv[row] ----------
__global__ __launch_bounds__(256) void k_gemm(const float* __restrict__ X,
                                              const float* __restrict__ W,
                                              const float* __restrict__ dinv,
                                              float* __restrict__ H) {
    __shared__ float Wl[64 * 128];
    __shared__ float Xt[64 * 32];
    const int t  = threadIdx.x;
    const int tc = t & 31;
    const int tr = t >> 5;
    const long long row0 = (long long)blockIdx.x * 32;
    float acc[4][4] = {};
    for (int kc = 0; kc < 128; kc += 64) {
        __syncthreads();
        {
            const float4* Wv = (const float4*)(W + kc * 128);
            float4* Wd = (float4*)Wl;
            for (int i = t; i < 2048; i += 256) Wd[i] = Wv[i];
        }
        {
            for (int idx = t; idx < 512; idx += 256) {
                int r  = idx >> 4;
                int kq = idx & 15;
                float4 v = *(const float4*)(X + (row0 + r) * 128 + kc + kq * 4);
                Xt[(kq * 4 + 0) * 32 + r] = v.x;
                Xt[(kq * 4 + 1) * 32 + r] = v.y;
                Xt[(kq * 4 + 2) * 32 + r] = v.z;
                Xt[(kq * 4 + 3) * 32 + r] = v.w;
            }
        }
        __syncthreads();
        #pragma unroll 8
        for (int k = 0; k < 64; ++k) {
            float4 w  = *(const float4*)(Wl + k * 128 + tc * 4);
            float4 xr = *(const float4*)(Xt + k * 32 + tr * 4);
            float xv[4] = {xr.x, xr.y, xr.z, xr.w};
            float wv[4] = {w.x, w.y, w.z, w.w};
            #pragma unroll
            for (int i = 0; i < 4; ++i)
                #pragma unroll
                for (int j = 0; j < 4; ++j)
                    acc[i][j] = fmaf(xv[i], wv[j], acc[i][j]);
        }
    }
    #pragma unroll
    for (int i = 0; i < 4; ++i) {
        float dv = dinv[row0 + tr * 4 + i];
        float* Hp = H + (row0 + tr * 4 + i) * 128 + tc * 4;
        float4 o = {acc[i][0] * dv, acc[i][1] * dv, acc[i][2] * dv, acc[i][3] * dv};
        *(float4*)Hp = o;
    }
}

// ---------------- aggregate ----------------
// h pre-scaled by dinv[src]:  out[d] = relu((sum_s h[s] + h[d]) * dinv[d] + b)
// 2 nodes per wave: 32 lanes x float4 each; 4 rows in flight per half-wave.
__global__ __launch_bounds__(256) void k_agg(const float* __restrict__ h,
                                             const int* __restrict__ rowstart,
                                             const int* __restrict__ csr_src,
                                             const float* __restrict__ dinv,
                                             const float* __restrict__ bias,
                                             float* __restrict__ out, int n) {
    const int wid  = threadIdx.x >> 6;
    const int half = (threadIdx.x >> 5) & 1;
    const int sub  = threadIdx.x & 31;
    const int node = blockIdx.x * 8 + wid * 2 + half;
    if (node >= n) return;
    const float di = dinv[node];
    int e = rowstart[node];
    const int end = rowstart[node + 1];
    const float4* __restrict__ hv = (const float4*)h;
    float4 a0 = hv[(size_t)node * 32 + sub];   // self (pre-scaled)
    float4 a1 = {0, 0, 0, 0}, a2 = {0, 0, 0, 0}, a3 = {0, 0, 0, 0};
    for (; e + 4 <= end; e += 4) {
        int s0 = csr_src[e + 0];
        int s1 = csr_src[e + 1];
        int s2 = csr_src[e + 2];
        int s3 = csr_src[e + 3];
        float4 v0 = hv[(size_t)s0 * 32 + sub];
        float4 v1 = hv[(size_t)s1 * 32 + sub];
        float4 v2 = hv[(size_t)s2 * 32 + sub];
        float4 v3 = hv[(size_t)s3 * 32 + sub];
        a0.x += v0.x; a0.y += v0.y; a0.z += v0.z; a0.w += v0.w;
        a1.x += v1.x; a1.y += v1.y; a1.z += v1.z; a1.w += v1.w;
        a2.x += v2.x; a2.y += v2.y; a2.z += v2.z; a2.w += v2.w;
        a3.x += v3.x; a3.y += v3.y; a3.z += v3.z; a3.w += v3.w;
    }
    for (; e < end; ++e) {
        int s = csr_src[e];
        float4 v = hv[(size_t)s * 32 + sub];
        a0.x += v.x; a0.y += v.y; a0.z += v.z; a0.w += v.w;
    }
    float sx = (a0.x + a1.x) + (a2.x + a3.x);
    float sy = (a0.y + a1.y) + (a2.y + a3.y);
    float sz = (a0.z + a1.z) + (a2.z + a3.z);
    float sw = (a0.w + a1.w) + (a2.w + a3.w);
    float4 bv = ((const float4*)bias)[sub];
    float4 o;
    o.x = fmaxf(fmaf(sx, di, bv.x), 0.0f);
    o.y = fmaxf(fmaf(sy, di, bv.y), 0.0f);
    o.z = fmaxf(fmaf(sz, di, bv.z), 0.0f);
    o.w = fmaxf(fmaf(sw, di, bv.w), 0.0f);
    ((float4*)out)[(size_t)node * 32 + sub] = o;
}

// ---------------- launch ----------------

extern "C" void kernel_launch(void* const* d_in, const int* in_sizes, int n_in,
                              void* d_out, int out_size, void* d_ws, size_t ws_size,
                              hipStream_t stream) {
    const float* x   = (const float*)d_in[0];
    const int* edges = (const int*)d_in[1];
    const float* W1  = (const float*)d_in[2];
    const float* b1  = (const float*)d_in[3];
    const float* W2  = (const float*)d_in[4];
    const float* b2  = (const float*)d_in[5];
    const int E = in_sizes[1] / 2;
    const int N = GCN_N;
    const int* srcp = edges;
    const int* dstp = edges + E;
    const int NB = (N + 255) / 256;            // 391
    const int SB = (E + 255) / 256;            // 6250 scatter blocks

    char* ws = (char*)d_ws;
    int*   cnt      = (int*)(ws + 0);          // 400 KB
    int*   rowstart = (int*)(ws + 524288);     // 400 KB + 4
    float* dinvp    = (float*)(ws + 1048576);  // 400 KB
    int*   bsum     = (int*)(ws + 1474560);    // ~1.6 KB
    int*   bbase    = (int*)(ws + 1507328);    // ~1.6 KB
    int*   csr      = (int*)(ws + 2097152);    // 6.4 MB
    float* h1       = (float*)(ws + 8912896);  // 51.2 MB
    float* h2       = (float*)(ws + 60112896); // 51.2 MB (end ~111.3 MB)
    int*   rank     = (int*)(ws + 60112896);   // 6.4 MB, overlaps h2:
    // rank is dead after the fused scatter; h2 is first written by agg1 (later).

    hipMemsetAsync(cnt, 0, N * sizeof(int), stream);

    k_rank <<<SB, 256, 0, stream>>>(dstp, cnt, rank, E);
    k_bsum <<<NB, 256, 0, stream>>>(cnt, bsum, N);
    k_bscan<<<1, 512, 0, stream>>>(bsum, bbase, rowstart, NB, N);
    k_rows <<<NB, 256, 0, stream>>>(cnt, bbase, rowstart, dinvp, N);

    // layer 1 GEMM fused with the atomic-free CSR scatter
    k_gemm1_scatter<<<GEMM_BLOCKS + SB, 256, 0, stream>>>(
        x, W1, dinvp, h1, srcp, dstp, rank, rowstart, csr, E);
    k_agg<<<(N + 7) / 8, 256, 0, stream>>>(h1, rowstart, csr, dinvp, b1, h2, N);
    // layer 2
    k_gemm<<<GEMM_BLOCKS, 256, 0, stream>>>(h2, W2, dinvp, h1);
    k_agg<<<(N + 7) / 8, 256, 0, stream>>>(h1, rowstart, csr, dinvp, b2, (float*)d_out, N);
}

// Round 4
// 326.529 us; speedup vs baseline: 2.1753x; 1.3407x over previous
//
#include <hip/hip_runtime.h>
#include <hip/hip_bf16.h>

#define GCN_N 100000
#define GEMM_BLOCKS (GCN_N / 32)   // 3125

typedef unsigned short u16;
typedef unsigned int u32;

// ---- bf16 helpers (manual, RNE) ----
__device__ inline u16 f2bf(float f) {
    u32 u = __float_as_uint(f);
    return (u16)((u + 0x7fffu + ((u >> 16) & 1u)) >> 16);
}
__device__ inline float bf_lo(u32 u) { return __uint_as_float(u << 16); }
__device__ inline float bf_hi(u32 u) { return __uint_as_float(u & 0xffff0000u); }

// add 8 bf16 (packed in a float4) into acc[8]
__device__ inline void addu8(float* a, float4 v) {
    u32 u;
    u = __float_as_uint(v.x); a[0] += bf_lo(u); a[1] += bf_hi(u);
    u = __float_as_uint(v.y); a[2] += bf_lo(u); a[3] += bf_hi(u);
    u = __float_as_uint(v.z); a[4] += bf_lo(u); a[5] += bf_hi(u);
    u = __float_as_uint(v.w); a[6] += bf_lo(u); a[7] += bf_hi(u);
}
__device__ inline void setu8(float* a, float4 v) {
    u32 u;
    u = __float_as_uint(v.x); a[0] = bf_lo(u); a[1] = bf_hi(u);
    u = __float_as_uint(v.y); a[2] = bf_lo(u); a[3] = bf_hi(u);
    u = __float_as_uint(v.z); a[4] = bf_lo(u); a[5] = bf_hi(u);
    u = __float_as_uint(v.w); a[6] = bf_lo(u); a[7] = bf_hi(u);
}

// ---------------- CSR build ----------------

__global__ __launch_bounds__(256) void k_rank(const int* __restrict__ dst,
                                              int* __restrict__ cnt,
                                              int* __restrict__ rank, int E) {
    int i = blockIdx.x * 256 + threadIdx.x;
    if (i < E) rank[i] = atomicAdd(&cnt[dst[i]], 1);
}

__global__ __launch_bounds__(256) void k_bsum(const int* __restrict__ cnt,
                                              int* __restrict__ bsum, int n) {
    int i = blockIdx.x * 256 + threadIdx.x;
    int v = (i < n) ? cnt[i] : 0;
    #pragma unroll
    for (int off = 32; off > 0; off >>= 1) v += __shfl_down(v, off, 64);
    __shared__ int ws[4];
    const int lane = threadIdx.x & 63, wid = threadIdx.x >> 6;
    if (lane == 0) ws[wid] = v;
    __syncthreads();
    if (threadIdx.x == 0) bsum[blockIdx.x] = ws[0] + ws[1] + ws[2] + ws[3];
}

__global__ __launch_bounds__(512) void k_bscan(const int* __restrict__ bsum,
                                               int* __restrict__ bbase,
                                               int* __restrict__ rowstart,
                                               int nb, int n) {
    __shared__ int wsum[8];
    __shared__ int woff[8];
    __shared__ int total;
    const int lane = threadIdx.x & 63, wid = threadIdx.x >> 6;
    int v = (threadIdx.x < nb) ? bsum[threadIdx.x] : 0;
    int s = v;
    #pragma unroll
    for (int off = 1; off < 64; off <<= 1) {
        int t = __shfl_up(s, off, 64);
        if (lane >= off) s += t;
    }
    if (lane == 63) wsum[wid] = s;
    __syncthreads();
    if (threadIdx.x == 0) {
        int run = 0;
        #pragma unroll
        for (int w = 0; w < 8; ++w) { int t = wsum[w]; woff[w] = run; run += t; }
        total = run;
    }
    __syncthreads();
    if (threadIdx.x < nb) bbase[threadIdx.x] = woff[wid] + (s - v);
    if (threadIdx.x == 0) rowstart[n] = total;
}

__global__ __launch_bounds__(256) void k_rows(const int* __restrict__ cnt,
                                              const int* __restrict__ bbase,
                                              int* __restrict__ rowstart,
                                              float* __restrict__ dinv, int n) {
    __shared__ int wsum[4];
    __shared__ int woff[4];
    const int lane = threadIdx.x & 63, wid = threadIdx.x >> 6;
    int i = blockIdx.x * 256 + threadIdx.x;
    int v = (i < n) ? cnt[i] : 0;
    int s = v;
    #pragma unroll
    for (int off = 1; off < 64; off <<= 1) {
        int t = __shfl_up(s, off, 64);
        if (lane >= off) s += t;
    }
    if (lane == 63) wsum[wid] = s;
    __syncthreads();
    if (threadIdx.x == 0) {
        int run = bbase[blockIdx.x];
        #pragma unroll
        for (int w = 0; w < 4; ++w) { int t = wsum[w]; woff[w] = run; run += t; }
    }
    __syncthreads();
    if (i < n) {
        rowstart[i] = woff[wid] + (s - v);
        dinv[i] = rsqrtf((float)(v + 1));   // +1 self-loop
    }
}

// ---------------- fused: GEMM1 (x f32 @ W1, *dinv, -> bf16) + CSR scatter ----
__global__ __launch_bounds__(256) void k_gemm1_scatter(
        const float* __restrict__ X, const float* __restrict__ W,
        const float* __restrict__ dinv, u16* __restrict__ H,
        const int* __restrict__ src, const int* __restrict__ dst,
        const int* __restrict__ rank, const int* __restrict__ rowstart,
        int* __restrict__ csr_src, int E) {
    __shared__ float Wl[64 * 128];   // 32 KB
    __shared__ float Xt[64 * 32];    //  8 KB
    if (blockIdx.x >= GEMM_BLOCKS) {
        int i = (blockIdx.x - GEMM_BLOCKS) * 256 + threadIdx.x;
        if (i < E) {
            int d = dst[i];
            csr_src[rowstart[d] + rank[i]] = src[i];   // no atomic
        }
        return;
    }
    const int t  = threadIdx.x;
    const int tc = t & 31;
    const int tr = t >> 5;
    const long long row0 = (long long)blockIdx.x * 32;
    float acc[4][4] = {};
    for (int kc = 0; kc < 128; kc += 64) {
        __syncthreads();
        {
            const float4* Wv = (const float4*)(W + kc * 128);
            float4* Wd = (float4*)Wl;
            for (int i = t; i < 2048; i += 256) Wd[i] = Wv[i];
        }
        {
            for (int idx = t; idx < 512; idx += 256) {
                int r  = idx >> 4;
                int kq = idx & 15;
                float4 v = *(const float4*)(X + (row0 + r) * 128 + kc + kq * 4);
                Xt[(kq * 4 + 0) * 32 + r] = v.x;
                Xt[(kq * 4 + 1) * 32 + r] = v.y;
                Xt[(kq * 4 + 2) * 32 + r] = v.z;
                Xt[(kq * 4 + 3) * 32 + r] = v.w;
            }
        }
        __syncthreads();
        #pragma unroll 8
        for (int k = 0; k < 64; ++k) {
            float4 w  = *(const float4*)(Wl + k * 128 + tc * 4);
            float4 xr = *(const float4*)(Xt + k * 32 + tr * 4);
            float xv[4] = {xr.x, xr.y, xr.z, xr.w};
            float wv[4] = {w.x, w.y, w.z, w.w};
            #pragma unroll
            for (int i = 0; i < 4; ++i)
                #pragma unroll
                for (int j = 0; j < 4; ++j)
                    acc[i][j] = fmaf(xv[i], wv[j], acc[i][j]);
        }
    }
    #pragma unroll
    for (int i = 0; i < 4; ++i) {
        float dv = dinv[row0 + tr * 4 + i];
        u32 p0 = (u32)f2bf(acc[i][0] * dv) | ((u32)f2bf(acc[i][1] * dv) << 16);
        u32 p1 = (u32)f2bf(acc[i][2] * dv) | ((u32)f2bf(acc[i][3] * dv) << 16);
        uint2 o; o.x = p0; o.y = p1;
        *(uint2*)(H + (size_t)(row0 + tr * 4 + i) * 128 + tc * 4) = o;
    }
}

// ---------------- GEMM (layer 2): X bf16 -> H bf16, *dinv[row] ----------
__global__ __launch_bounds__(256) void k_gemm_bf(const u16* __restrict__ X,
                                                 const float* __restrict__ W,
                                                 const float* __restrict__ dinv,
                                                 u16* __restrict__ H) {
    __shared__ float Wl[64 * 128];
    __shared__ float Xt[64 * 32];
    const int t  = threadIdx.x;
    const int tc = t & 31;
    const int tr = t >> 5;
    const long long row0 = (long long)blockIdx.x * 32;
    float acc[4][4] = {};
    for (int kc = 0; kc < 128; kc += 64) {
        __syncthreads();
        {
            const float4* Wv = (const float4*)(W + kc * 128);
            float4* Wd = (float4*)Wl;
            for (int i = t; i < 2048; i += 256) Wd[i] = Wv[i];
        }
        {
            for (int idx = t; idx < 512; idx += 256) {
                int r  = idx >> 4;
                int kq = idx & 15;
                uint2 v = *(const uint2*)(X + (row0 + r) * 128 + kc + kq * 4);
                Xt[(kq * 4 + 0) * 32 + r] = bf_lo(v.x);
                Xt[(kq * 4 + 1) * 32 + r] = bf_hi(v.x);
                Xt[(kq * 4 + 2) * 32 + r] = bf_lo(v.y);
                Xt[(kq * 4 + 3) * 32 + r] = bf_hi(v.y);
            }
        }
        __syncthreads();
        #pragma unroll 8
        for (int k = 0; k < 64; ++k) {
            float4 w  = *(const float4*)(Wl + k * 128 + tc * 4);
            float4 xr = *(const float4*)(Xt + k * 32 + tr * 4);
            float xv[4] = {xr.x, xr.y, xr.z, xr.w};
            float wv[4] = {w.x, w.y, w.z, w.w};
            #pragma unroll
            for (int i = 0; i < 4; ++i)
                #pragma unroll
                for (int j = 0; j < 4; ++j)
                    acc[i][j] = fmaf(xv[i], wv[j], acc[i][j]);
        }
    }
    #pragma unroll
    for (int i = 0; i < 4; ++i) {
        float dv = dinv[row0 + tr * 4 + i];
        u32 p0 = (u32)f2bf(acc[i][0] * dv) | ((u32)f2bf(acc[i][1] * dv) << 16);
        u32 p1 = (u32)f2bf(acc[i][2] * dv) | ((u32)f2bf(acc[i][3] * dv) << 16);
        uint2 o; o.x = p0; o.y = p1;
        *(uint2*)(H + (size_t)(row0 + tr * 4 + i) * 128 + tc * 4) = o;
    }
}

// ---------------- aggregate (bf16 rows) ----------------
// h pre-scaled by dinv[src]: out[d] = relu((sum_s h[s] + h[d]) * dinv[d] + b)
// 4 nodes/wave: 16 lanes x 16 B (8 bf16 channels) per node; 4-deep unroll.
template<int OUT_BF16>
__global__ __launch_bounds__(256) void k_agg(const u16* __restrict__ h,
                                             const int* __restrict__ rowstart,
                                             const int* __restrict__ csr_src,
                                             const float* __restrict__ dinv,
                                             const float* __restrict__ bias,
                                             void* __restrict__ outp, int n) {
    const int q    = threadIdx.x >> 4;   // 0..15 (node slot in block)
    const int sub  = threadIdx.x & 15;   // channel group
    const int node = blockIdx.x * 16 + q;
    if (node >= n) return;
    const float di = dinv[node];
    int e = rowstart[node];
    const int end = rowstart[node + 1];
    const float4* __restrict__ hv = (const float4*)h;   // 16 x float4 per row
    float a[8], b[8];
    setu8(a, hv[(size_t)node * 16 + sub]);              // self (pre-scaled)
    #pragma unroll
    for (int j = 0; j < 8; ++j) b[j] = 0.f;
    for (; e + 4 <= end; e += 4) {
        int s0 = csr_src[e + 0];
        int s1 = csr_src[e + 1];
        int s2 = csr_src[e + 2];
        int s3 = csr_src[e + 3];
        float4 v0 = hv[(size_t)s0 * 16 + sub];
        float4 v1 = hv[(size_t)s1 * 16 + sub];
        float4 v2 = hv[(size_t)s2 * 16 + sub];
        float4 v3 = hv[(size_t)s3 * 16 + sub];
        addu8(a, v0); addu8(b, v1); addu8(a, v2); addu8(b, v3);
    }
    for (; e < end; ++e) {
        float4 v = hv[(size_t)csr_src[e] * 16 + sub];
        addu8(a, v);
    }
    const float4 bv0 = ((const float4*)bias)[sub * 2];
    const float4 bv1 = ((const float4*)bias)[sub * 2 + 1];
    float o[8];
    o[0] = fmaxf(fmaf(a[0] + b[0], di, bv0.x), 0.f);
    o[1] = fmaxf(fmaf(a[1] + b[1], di, bv0.y), 0.f);
    o[2] = fmaxf(fmaf(a[2] + b[2], di, bv0.z), 0.f);
    o[3] = fmaxf(fmaf(a[3] + b[3], di, bv0.w), 0.f);
    o[4] = fmaxf(fmaf(a[4] + b[4], di, bv1.x), 0.f);
    o[5] = fmaxf(fmaf(a[5] + b[5], di, bv1.y), 0.f);
    o[6] = fmaxf(fmaf(a[6] + b[6], di, bv1.z), 0.f);
    o[7] = fmaxf(fmaf(a[7] + b[7], di, bv1.w), 0.f);
    if (OUT_BF16) {
        u32 p0 = (u32)f2bf(o[0]) | ((u32)f2bf(o[1]) << 16);
        u32 p1 = (u32)f2bf(o[2]) | ((u32)f2bf(o[3]) << 16);
        u32 p2 = (u32)f2bf(o[4]) | ((u32)f2bf(o[5]) << 16);
        u32 p3 = (u32)f2bf(o[6]) | ((u32)f2bf(o[7]) << 16);
        float4 pv;
        pv.x = __uint_as_float(p0); pv.y = __uint_as_float(p1);
        pv.z = __uint_as_float(p2); pv.w = __uint_as_float(p3);
        ((float4*)outp)[(size_t)node * 16 + sub] = pv;
    } else {
        float* out = (float*)outp + (size_t)node * 128 + sub * 8;
        float4 w0 = {o[0], o[1], o[2], o[3]};
        float4 w1 = {o[4], o[5], o[6], o[7]};
        *(float4*)(out + 0) = w0;
        *(float4*)(out + 4) = w1;
    }
}

// ---------------- launch ----------------

extern "C" void kernel_launch(void* const* d_in, const int* in_sizes, int n_in,
                              void* d_out, int out_size, void* d_ws, size_t ws_size,
                              hipStream_t stream) {
    const float* x   = (const float*)d_in[0];
    const int* edges = (const int*)d_in[1];
    const float* W1  = (const float*)d_in[2];
    const float* b1  = (const float*)d_in[3];
    const float* W2  = (const float*)d_in[4];
    const float* b2  = (const float*)d_in[5];
    const int E = in_sizes[1] / 2;
    const int N = GCN_N;
    const int* srcp = edges;
    const int* dstp = edges + E;
    const int NB = (N + 255) / 256;            // 391
    const int SB = (E + 255) / 256;            // 6250

    char* ws = (char*)d_ws;
    int*   cnt      = (int*)(ws + 0);          // 400 KB
    int*   rowstart = (int*)(ws + 524288);     // 400 KB + 4
    float* dinvp    = (float*)(ws + 1048576);  // 400 KB
    int*   bsum     = (int*)(ws + 1474560);
    int*   bbase    = (int*)(ws + 1507328);
    int*   csr      = (int*)(ws + 2097152);    // 6.4 MB
    int*   rank     = (int*)(ws + 8912896);    // 6.4 MB
    u16*   h1       = (u16*)(ws + 16777216);   // 25.6 MB bf16
    u16*   h2       = (u16*)(ws + 44040192);   // 25.6 MB bf16 (end ~69.6 MB)
    // h3 (gemm2 out) reuses h1: h1 dead after agg1.

    hipMemsetAsync(cnt, 0, N * sizeof(int), stream);

    k_rank <<<SB, 256, 0, stream>>>(dstp, cnt, rank, E);
    k_bsum <<<NB, 256, 0, stream>>>(cnt, bsum, N);
    k_bscan<<<1, 512, 0, stream>>>(bsum, bbase, rowstart, NB, N);
    k_rows <<<NB, 256, 0, stream>>>(cnt, bbase, rowstart, dinvp, N);

    // layer 1 GEMM fused with atomic-free CSR scatter
    k_gemm1_scatter<<<GEMM_BLOCKS + SB, 256, 0, stream>>>(
        x, W1, dinvp, h1, srcp, dstp, rank, rowstart, csr, E);
    k_agg<1><<<(N + 15) / 16, 256, 0, stream>>>(h1, rowstart, csr, dinvp, b1, h2, N);
    // layer 2
    k_gemm_bf<<<GEMM_BLOCKS, 256, 0, stream>>>(h2, W2, dinvp, h1);
    k_agg<0><<<(N + 15) / 16, 256, 0, stream>>>(h1, rowstart, csr, dinvp, b2, d_out, N);
}

// Round 6
// 321.169 us; speedup vs baseline: 2.2116x; 1.0167x over previous
//
#include <hip/hip_runtime.h>
#include <hip/hip_bf16.h>

#define GCN_N 100000
#define GB1 1563   // ceil(100000 / 64) gemm blocks (64 rows each)

typedef unsigned short u16;
typedef unsigned int u32;
typedef float f32x4 __attribute__((ext_vector_type(4)));
typedef short bf16x8 __attribute__((ext_vector_type(8)));

union v16 { uint4 u; bf16x8 h; };

// ---- bf16 helpers (manual, RNE) ----
__device__ inline u16 f2bf(float f) {
    u32 u = __float_as_uint(f);
    return (u16)((u + 0x7fffu + ((u >> 16) & 1u)) >> 16);
}
__device__ inline u32 pack2(float a, float b) {
    return (u32)f2bf(a) | ((u32)f2bf(b) << 16);
}
__device__ inline float bf_lo(u32 u) { return __uint_as_float(u << 16); }
__device__ inline float bf_hi(u32 u) { return __uint_as_float(u & 0xffff0000u); }

__device__ inline void addu8(float* a, float4 v) {
    u32 u;
    u = __float_as_uint(v.x); a[0] += bf_lo(u); a[1] += bf_hi(u);
    u = __float_as_uint(v.y); a[2] += bf_lo(u); a[3] += bf_hi(u);
    u = __float_as_uint(v.z); a[4] += bf_lo(u); a[5] += bf_hi(u);
    u = __float_as_uint(v.w); a[6] += bf_lo(u); a[7] += bf_hi(u);
}
__device__ inline void setu8(float* a, float4 v) {
    u32 u;
    u = __float_as_uint(v.x); a[0] = bf_lo(u); a[1] = bf_hi(u);
    u = __float_as_uint(v.y); a[2] = bf_lo(u); a[3] = bf_hi(u);
    u = __float_as_uint(v.z); a[4] = bf_lo(u); a[5] = bf_hi(u);
    u = __float_as_uint(v.w); a[6] = bf_lo(u); a[7] = bf_hi(u);
}

// MFMA via the gfx950 builtin (compile-verified fragment types per guide §3).
__device__ inline void mfma16(f32x4& d, uint4 a, uint4 b) {
    v16 av, bv; av.u = a; bv.u = b;
    d = __builtin_amdgcn_mfma_f32_16x16x32_bf16(av.h, bv.h, d, 0, 0, 0);
}

// ---------------- CSR build ----------------

__global__ __launch_bounds__(256) void k_rank(const int* __restrict__ dst,
                                              int* __restrict__ cnt,
                                              int* __restrict__ rank, int E) {
    int i = blockIdx.x * 256 + threadIdx.x;
    if (i < E) rank[i] = atomicAdd(&cnt[dst[i]], 1);
}

__global__ __launch_bounds__(256) void k_bsum(const int* __restrict__ cnt,
                                              int* __restrict__ bsum, int n) {
    int i = blockIdx.x * 256 + threadIdx.x;
    int v = (i < n) ? cnt[i] : 0;
    #pragma unroll
    for (int off = 32; off > 0; off >>= 1) v += __shfl_down(v, off, 64);
    __shared__ int ws[4];
    const int lane = threadIdx.x & 63, wid = threadIdx.x >> 6;
    if (lane == 0) ws[wid] = v;
    __syncthreads();
    if (threadIdx.x == 0) bsum[blockIdx.x] = ws[0] + ws[1] + ws[2] + ws[3];
}

__global__ __launch_bounds__(512) void k_bscan(const int* __restrict__ bsum,
                                               int* __restrict__ bbase,
                                               int* __restrict__ rowstart,
                                               int nb, int n) {
    __shared__ int wsum[8];
    __shared__ int woff[8];
    __shared__ int total;
    const int lane = threadIdx.x & 63, wid = threadIdx.x >> 6;
    int v = (threadIdx.x < nb) ? bsum[threadIdx.x] : 0;
    int s = v;
    #pragma unroll
    for (int off = 1; off < 64; off <<= 1) {
        int t = __shfl_up(s, off, 64);
        if (lane >= off) s += t;
    }
    if (lane == 63) wsum[wid] = s;
    __syncthreads();
    if (threadIdx.x == 0) {
        int run = 0;
        #pragma unroll
        for (int w = 0; w < 8; ++w) { int t = wsum[w]; woff[w] = run; run += t; }
        total = run;
    }
    __syncthreads();
    if (threadIdx.x < nb) bbase[threadIdx.x] = woff[wid] + (s - v);
    if (threadIdx.x == 0) rowstart[n] = total;
}

__global__ __launch_bounds__(256) void k_rows(const int* __restrict__ cnt,
                                              const int* __restrict__ bbase,
                                              int* __restrict__ rowstart,
                                              float* __restrict__ dinv, int n) {
    __shared__ int wsum[4];
    __shared__ int woff[4];
    const int lane = threadIdx.x & 63, wid = threadIdx.x >> 6;
    int i = blockIdx.x * 256 + threadIdx.x;
    int v = (i < n) ? cnt[i] : 0;
    int s = v;
    #pragma unroll
    for (int off = 1; off < 64; off <<= 1) {
        int t = __shfl_up(s, off, 64);
        if (lane >= off) s += t;
    }
    if (lane == 63) wsum[wid] = s;
    __syncthreads();
    if (threadIdx.x == 0) {
        int run = bbase[blockIdx.x];
        #pragma unroll
        for (int w = 0; w < 4; ++w) { int t = wsum[w]; woff[w] = run; run += t; }
    }
    __syncthreads();
    if (i < n) {
        rowstart[i] = woff[wid] + (s - v);
        dinv[i] = rsqrtf((float)(v + 1));   // +1 self-loop
    }
}

// ---------------- W -> Wt bf16 transposed [n][k] (once, tiny) ----------------
__global__ __launch_bounds__(256) void k_wprep(const float* __restrict__ W1,
                                               const float* __restrict__ W2,
                                               u16* __restrict__ Wt1,
                                               u16* __restrict__ Wt2) {
    const float* W = blockIdx.x ? W2 : W1;
    u16* Wt = blockIdx.x ? Wt2 : Wt1;
    for (int i = threadIdx.x; i < 16384; i += 256) {
        int k = i >> 7, nn = i & 127;
        Wt[nn * 128 + k] = f2bf(W[i]);
    }
}

// ---------------- MFMA GEMM core: 64 rows x 128 cols, K=128 ----------------
// Xs: LDS 64x128 bf16, row-major, XOR-swizzled (byte ^= (row&7)<<4).
// Wt: global bf16 [n][k] (L2-resident). H: bf16 out, pre-scaled by dinv[row].
__device__ __attribute__((always_inline))
inline void gemm_core(const uint4* Xs, const u16* __restrict__ Wt,
                      const float* __restrict__ dinv, u16* __restrict__ H,
                      long long row0, int n) {
    const int t = threadIdx.x;
    const int wid = t >> 6;
    const int l = t & 63, lm = l & 15, lh = l >> 4;
    // A fragments: lane l holds A[row=lm][k=lh*8 .. +7] per kk-chunk
    uint4 a[4];
    const int lrow = wid * 16 + lm;
    #pragma unroll
    for (int kk = 0; kk < 4; ++kk) {
        int byte = (lrow * 256 + kk * 64 + lh * 16) ^ ((lm & 7) << 4);
        a[kk] = Xs[byte >> 4];
    }
    const uint4* wb = (const uint4*)Wt;
    f32x4 acc[8];
    #pragma unroll
    for (int j = 0; j < 8; ++j) acc[j] = (f32x4){0.f, 0.f, 0.f, 0.f};
    #pragma unroll
    for (int j = 0; j < 8; ++j) {
        #pragma unroll
        for (int kk = 0; kk < 4; ++kk) {
            // B fragment: lane l holds B[k=kk*32+lh*8 .. +7][col=j*16+lm]
            uint4 b = wb[(j * 16 + lm) * 16 + kk * 4 + lh];
            mfma16(acc[j], a[kk], b);
        }
    }
    // D: lane l, reg r -> row = lh*4 + r, col = j*16 + lm
    long long gr0 = row0 + wid * 16 + lh * 4;
    float dv[4];
    #pragma unroll
    for (int r = 0; r < 4; ++r) dv[r] = (gr0 + r < n) ? dinv[gr0 + r] : 0.f;
    #pragma unroll
    for (int j = 0; j < 8; ++j) {
        #pragma unroll
        for (int r = 0; r < 4; ++r) {
            long long grow = gr0 + r;
            if (grow < n) H[grow * 128 + j * 16 + lm] = f2bf(acc[j][r] * dv[r]);
        }
    }
}

// ---------------- fused: MFMA GEMM1 (f32 x -> bf16 h) + CSR scatter ----------
__global__ __launch_bounds__(256) void k_gemm1_scatter(
        const float* __restrict__ X, const u16* __restrict__ Wt,
        const float* __restrict__ dinv, u16* __restrict__ H,
        const int* __restrict__ src, const int* __restrict__ dst,
        const int* __restrict__ rank, const int* __restrict__ rowstart,
        int* __restrict__ csr_src, int E, int n) {
    __shared__ uint4 Xs[1024];   // 16 KB
    if (blockIdx.x >= GB1) {
        int i = (blockIdx.x - GB1) * 256 + threadIdx.x;
        if (i < E) csr_src[rowstart[dst[i]] + rank[i]] = src[i];   // no atomic
        return;
    }
    const long long row0 = (long long)blockIdx.x * 64;
    const int t = threadIdx.x;
    uint2* Xs2 = (uint2*)Xs;
    #pragma unroll
    for (int i = 0; i < 8; ++i) {
        int idx = i * 1024 + t * 4;          // f32 elem in 64x128 tile, coalesced
        int row = idx >> 7, k = idx & 127;
        long long grow = row0 + row; if (grow >= n) grow = n - 1;
        float4 v = *(const float4*)(X + grow * 128 + k);
        int byte = (row * 256 + k * 2) ^ ((row & 7) << 4);
        uint2 p; p.x = pack2(v.x, v.y); p.y = pack2(v.z, v.w);
        Xs2[byte >> 3] = p;
    }
    __syncthreads();
    gemm_core(Xs, Wt, dinv, H, row0, n);
}

// ---------------- MFMA GEMM2 (bf16 -> bf16) ----------------
__global__ __launch_bounds__(256) void k_gemm2(
        const u16* __restrict__ X, const u16* __restrict__ Wt,
        const float* __restrict__ dinv, u16* __restrict__ H, int n) {
    __shared__ uint4 Xs[1024];   // 16 KB
    const long long row0 = (long long)blockIdx.x * 64;
    const int t = threadIdx.x;
    #pragma unroll
    for (int i = 0; i < 4; ++i) {
        int idx = i * 2048 + t * 8;          // bf16 elem index, coalesced b128
        int row = idx >> 7, k = idx & 127;
        long long grow = row0 + row; if (grow >= n) grow = n - 1;
        uint4 v = *(const uint4*)(X + grow * 128 + k);
        int byte = (row * 256 + k * 2) ^ ((row & 7) << 4);
        Xs[byte >> 4] = v;
    }
    __syncthreads();
    gemm_core(Xs, Wt, dinv, H, row0, n);
}

// ---------------- aggregate (bf16 rows), 8-deep gather pipeline --------------
// h pre-scaled by dinv[src]: out[d] = relu((sum_s h[s] + h[d]) * dinv[d] + b)
template<int OUT_BF16>
__global__ __launch_bounds__(256) void k_agg(const u16* __restrict__ h,
                                             const int* __restrict__ rowstart,
                                             const int* __restrict__ csr_src,
                                             const float* __restrict__ dinv,
                                             const float* __restrict__ bias,
                                             void* __restrict__ outp, int n) {
    const int q    = threadIdx.x >> 4;   // node slot in block
    const int sub  = threadIdx.x & 15;   // channel group (8 bf16)
    const int node = blockIdx.x * 16 + q;
    if (node >= n) return;
    const float di = dinv[node];
    int e = rowstart[node];
    const int end = rowstart[node + 1];
    const float4* __restrict__ hv = (const float4*)h;   // 16 x 16B per row
    float a[8], b[8];
    setu8(a, hv[(size_t)node * 16 + sub]);              // self (pre-scaled)
    #pragma unroll
    for (int j = 0; j < 8; ++j) b[j] = 0.f;
    for (; e + 8 <= end; e += 8) {
        int s0 = csr_src[e + 0], s1 = csr_src[e + 1];
        int s2 = csr_src[e + 2], s3 = csr_src[e + 3];
        int s4 = csr_src[e + 4], s5 = csr_src[e + 5];
        int s6 = csr_src[e + 6], s7 = csr_src[e + 7];
        float4 v0 = hv[(size_t)s0 * 16 + sub];
        float4 v1 = hv[(size_t)s1 * 16 + sub];
        float4 v2 = hv[(size_t)s2 * 16 + sub];
        float4 v3 = hv[(size_t)s3 * 16 + sub];
        float4 v4 = hv[(size_t)s4 * 16 + sub];
        float4 v5 = hv[(size_t)s5 * 16 + sub];
        float4 v6 = hv[(size_t)s6 * 16 + sub];
        float4 v7 = hv[(size_t)s7 * 16 + sub];
        addu8(a, v0); addu8(b, v1); addu8(a, v2); addu8(b, v3);
        addu8(a, v4); addu8(b, v5); addu8(a, v6); addu8(b, v7);
    }
    for (; e + 4 <= end; e += 4) {
        int s0 = csr_src[e + 0], s1 = csr_src[e + 1];
        int s2 = csr_src[e + 2], s3 = csr_src[e + 3];
        float4 v0 = hv[(size_t)s0 * 16 + sub];
        float4 v1 = hv[(size_t)s1 * 16 + sub];
        float4 v2 = hv[(size_t)s2 * 16 + sub];
        float4 v3 = hv[(size_t)s3 * 16 + sub];
        addu8(a, v0); addu8(b, v1); addu8(a, v2); addu8(b, v3);
    }
    for (; e < end; ++e) {
        float4 v = hv[(size_t)csr_src[e] * 16 + sub];
        addu8(a, v);
    }
    const float4 bv0 = ((const float4*)bias)[sub * 2];
    const float4 bv1 = ((const float4*)bias)[sub * 2 + 1];
    float o[8];
    o[0] = fmaxf(fmaf(a[0] + b[0], di, bv0.x), 0.f);
    o[1] = fmaxf(fmaf(a[1] + b[1], di, bv0.y), 0.f);
    o[2] = fmaxf(fmaf(a[2] + b[2], di, bv0.z), 0.f);
    o[3] = fmaxf(fmaf(a[3] + b[3], di, bv0.w), 0.f);
    o[4] = fmaxf(fmaf(a[4] + b[4], di, bv1.x), 0.f);
    o[5] = fmaxf(fmaf(a[5] + b[5], di, bv1.y), 0.f);
    o[6] = fmaxf(fmaf(a[6] + b[6], di, bv1.z), 0.f);
    o[7] = fmaxf(fmaf(a[7] + b[7], di, bv1.w), 0.f);
    if (OUT_BF16) {
        float4 pv;
        pv.x = __uint_as_float(pack2(o[0], o[1]));
        pv.y = __uint_as_float(pack2(o[2], o[3]));
        pv.z = __uint_as_float(pack2(o[4], o[5]));
        pv.w = __uint_as_float(pack2(o[6], o[7]));
        ((float4*)outp)[(size_t)node * 16 + sub] = pv;
    } else {
        float* out = (float*)outp + (size_t)node * 128 + sub * 8;
        float4 w0 = {o[0], o[1], o[2], o[3]};
        float4 w1 = {o[4], o[5], o[6], o[7]};
        *(float4*)(out + 0) = w0;
        *(float4*)(out + 4) = w1;
    }
}

// ---------------- launch ----------------

extern "C" void kernel_launch(void* const* d_in, const int* in_sizes, int n_in,
                              void* d_out, int out_size, void* d_ws, size_t ws_size,
                              hipStream_t stream) {
    const float* x   = (const float*)d_in[0];
    const int* edges = (const int*)d_in[1];
    const float* W1  = (const float*)d_in[2];
    const float* b1  = (const float*)d_in[3];
    const float* W2  = (const float*)d_in[4];
    const float* b2  = (const float*)d_in[5];
    const int E = in_sizes[1] / 2;
    const int N = GCN_N;
    const int* srcp = edges;
    const int* dstp = edges + E;
    const int NB = (N + 255) / 256;            // 391
    const int SB = (E + 255) / 256;            // 6250

    char* ws = (char*)d_ws;
    int*   cnt      = (int*)(ws + 0);          // 400 KB
    int*   rowstart = (int*)(ws + 524288);     // 400 KB + 4
    float* dinvp    = (float*)(ws + 1048576);  // 400 KB
    int*   bsum     = (int*)(ws + 1474560);
    int*   bbase    = (int*)(ws + 1507328);
    u16*   wt1      = (u16*)(ws + 1572864);    // 32 KB
    u16*   wt2      = (u16*)(ws + 1605632);    // 32 KB
    int*   csr      = (int*)(ws + 2097152);    // 6.4 MB
    int*   rank     = (int*)(ws + 8912896);    // 6.4 MB
    u16*   h1       = (u16*)(ws + 16777216);   // 25.6 MB bf16
    u16*   h2       = (u16*)(ws + 44040192);   // 25.6 MB bf16 (end ~69.6 MB)

    hipMemsetAsync(cnt, 0, N * sizeof(int), stream);

    k_rank <<<SB, 256, 0, stream>>>(dstp, cnt, rank, E);
    k_bsum <<<NB, 256, 0, stream>>>(cnt, bsum, N);
    k_bscan<<<1, 512, 0, stream>>>(bsum, bbase, rowstart, NB, N);
    k_rows <<<NB, 256, 0, stream>>>(cnt, bbase, rowstart, dinvp, N);
    k_wprep<<<2, 256, 0, stream>>>(W1, W2, wt1, wt2);

    // layer 1 MFMA GEMM fused with atomic-free CSR scatter
    k_gemm1_scatter<<<GB1 + SB, 256, 0, stream>>>(
        x, wt1, dinvp, h1, srcp, dstp, rank, rowstart, csr, E, N);
    k_agg<1><<<(N + 15) / 16, 256, 0, stream>>>(h1, rowstart, csr, dinvp, b1, h2, N);
    // layer 2
    k_gemm2<<<GB1, 256, 0, stream>>>(h2, wt2, dinvp, h1, N);
    k_agg<0><<<(N + 15) / 16, 256, 0, stream>>>(h1, rowstart, csr, dinvp, b2, d_out, N);
}